// Round 1
// baseline (323.586 us; speedup 1.0000x reference)
//
#include <hip/hip_runtime.h>

#define NB 65536
#define NT 512
#define SLEN 12

// One thread per series row. Memory-bound: 268 MB total traffic, ~43 us floor.
// VPC=8 float4s (128 B) per chunk => 8 outstanding loads/thread for latency
// hiding at 1 wave/SIMD occupancy.
__global__ __launch_bounds__(256) void holtwinters_kernel(
    const float* __restrict__ series,
    const int*   __restrict__ shifts,
    const float* __restrict__ alpha_p,
    const float* __restrict__ beta_p,
    const float* __restrict__ init_season,
    const float* __restrict__ trend0_p,
    float*       __restrict__ out)
{
    __shared__ float ss[SLEN];
    if (threadIdx.x < SLEN) ss[threadIdx.x] = init_season[threadIdx.x];
    __syncthreads();

    const int b = blockIdx.x * blockDim.x + threadIdx.x;

    const float alpha  = alpha_p[0];
    const float beta   = beta_p[0];
    const float oma    = 1.0f - alpha;
    const float omb    = 1.0f - beta;
    const float trend0 = trend0_p[0];

    const int shift = shifts[b];
    // season index at t=0: (0 - shift) mod 12
    int sidx = (SLEN - (shift % SLEN)) % SLEN;

    const float4* __restrict__ src = (const float4*)(series + (size_t)b * NT);
    float4*       __restrict__ dst = (float4*)(out + (size_t)b * NT);

    constexpr int VPC = 8;               // float4s per chunk (128 B/thread burst)
    constexpr int NCH = NT / (4 * VPC);  // 16 chunks

    float4 cur[VPC], nxt[VPC];
    #pragma unroll
    for (int j = 0; j < VPC; ++j) cur[j] = src[j];

    float smooth = 0.0f, trend = 0.0f;

    for (int c = 0; c < NCH; ++c) {
        // prefetch next chunk early so loads overlap the serial compute below
        if (c + 1 < NCH) {
            #pragma unroll
            for (int j = 0; j < VPC; ++j) nxt[j] = src[(c + 1) * VPC + j];
        }

        float4 rr[VPC];
        #pragma unroll
        for (int j = 0; j < VPC; ++j) {
            float y[4] = {cur[j].x, cur[j].y, cur[j].z, cur[j].w};
            float o[4];
            #pragma unroll
            for (int k = 0; k < 4; ++k) {
                const float s = ss[sidx];
                sidx = (sidx + 1 == SLEN) ? 0 : sidx + 1;
                if (c == 0 && j == 0 && k == 0) {
                    // t == 0: res0 = y0 + init_trend, season not added
                    smooth = y[0];
                    trend  = trend0;
                    o[0]   = smooth + trend;
                } else {
                    const float st     = smooth + trend;
                    const float sm_new = alpha * (y[k] - s) + oma * st;
                    trend  = beta * (sm_new - smooth) + omb * trend;
                    smooth = sm_new;
                    o[k]   = sm_new + trend + s;
                }
            }
            rr[j] = make_float4(o[0], o[1], o[2], o[3]);
        }

        #pragma unroll
        for (int j = 0; j < VPC; ++j) dst[c * VPC + j] = rr[j];
        #pragma unroll
        for (int j = 0; j < VPC; ++j) cur[j] = nxt[j];
    }
}

extern "C" void kernel_launch(void* const* d_in, const int* in_sizes, int n_in,
                              void* d_out, int out_size, void* d_ws, size_t ws_size,
                              hipStream_t stream) {
    // inputs: 0=series(B*T f32), 1=series_shifts(B i32), 2=alpha, 3=beta,
    //         4=gamma(unused), 5=init_season(12 f32), 6=init_trend, 7=n_preds(unused)
    const float* series      = (const float*)d_in[0];
    const int*   shifts      = (const int*)  d_in[1];
    const float* alpha       = (const float*)d_in[2];
    const float* beta        = (const float*)d_in[3];
    const float* init_season = (const float*)d_in[5];
    const float* init_trend  = (const float*)d_in[6];
    float*       out         = (float*)d_out;

    dim3 block(256);
    dim3 grid(NB / 256);
    hipLaunchKernelGGL(holtwinters_kernel, grid, block, 0, stream,
                       series, shifts, alpha, beta, init_season, init_trend, out);
}

// Round 2
// 265.739 us; speedup vs baseline: 1.2177x; 1.2177x over previous
//
#include <hip/hip_runtime.h>

#define NB 65536
#define NT 512
#define SLEN 12
#define BLOCK 256
#define TCOLS 32             // columns per tile
#define NTILE (NT / TCOLS)   // 16 tiles
#define LSTRIDE 36           // 32 cols + 4 pad: rows stay 16B-aligned, banks spread uniformly

// Block = 256 threads = 256 rows. Per tile: coalesced global<->LDS transpose,
// serial Holt-Winters recurrence runs per-thread on its own LDS row in place.
__global__ __launch_bounds__(BLOCK) void holtwinters_kernel(
    const float* __restrict__ series,
    const int*   __restrict__ shifts,
    const float* __restrict__ alpha_p,
    const float* __restrict__ beta_p,
    const float* __restrict__ init_season,
    const float* __restrict__ trend0_p,
    float*       __restrict__ out)
{
    __shared__ float ss[SLEN];
    __shared__ __align__(16) float tile[BLOCK * LSTRIDE];  // 36 KB

    if (threadIdx.x < SLEN) ss[threadIdx.x] = init_season[threadIdx.x];

    const int t    = threadIdx.x;
    const int row0 = blockIdx.x * BLOCK;
    const int b    = row0 + t;

    const float alpha  = alpha_p[0];
    const float beta   = beta_p[0];
    const float oma    = 1.0f - alpha;
    const float omb    = 1.0f - beta;
    const float trend0 = trend0_p[0];

    const int shift = shifts[b];
    int sidx = (SLEN - (shift % SLEN)) % SLEN;   // season index at t=0

    // coalesced lane mapping: round j covers rows j*32..j*32+31; lanes 8k..8k+7
    // read 8 consecutive float4s (128 B) of one row segment.
    const int lrow = t >> 3;        // 0..31
    const int lcol = (t & 7) * 4;   // float offset within the 32-col segment

    // preload tile 0
    float4 nxt[8];
    #pragma unroll
    for (int j = 0; j < 8; ++j) {
        const int r = j * 32 + lrow;
        nxt[j] = *(const float4*)(series + (size_t)(row0 + r) * NT + lcol);
    }

    float smooth = 0.0f, trend = 0.0f;
    __syncthreads();  // ss ready

    for (int c = 0; c < NTILE; ++c) {
        // stage regs -> LDS (transposed access comes later)
        #pragma unroll
        for (int j = 0; j < 8; ++j) {
            const int r = j * 32 + lrow;
            *(float4*)&tile[r * LSTRIDE + lcol] = nxt[j];
        }
        __syncthreads();

        // prefetch next tile early so loads overlap compute + store phases
        if (c + 1 < NTILE) {
            #pragma unroll
            for (int j = 0; j < 8; ++j) {
                const int r = j * 32 + lrow;
                nxt[j] = *(const float4*)(series + (size_t)(row0 + r) * NT
                                          + (c + 1) * TCOLS + lcol);
            }
        }

        // own row: 32 serial recurrence steps, in place in LDS
        float v[TCOLS];
        #pragma unroll
        for (int q = 0; q < 8; ++q) {
            const float4 rd = *(const float4*)&tile[t * LSTRIDE + 4 * q];
            v[4*q+0] = rd.x; v[4*q+1] = rd.y; v[4*q+2] = rd.z; v[4*q+3] = rd.w;
        }
        #pragma unroll
        for (int k = 0; k < TCOLS; ++k) {
            const float s = ss[sidx];
            sidx = (sidx + 1 == SLEN) ? 0 : sidx + 1;
            const float y = v[k];
            if (k == 0 && c == 0) {
                // t == 0: res0 = y0 + init_trend, season not added
                smooth = y;
                trend  = trend0;
                v[0]   = smooth + trend;
            } else {
                const float st = smooth + trend;
                const float sm = alpha * (y - s) + oma * st;
                trend  = beta * (sm - smooth) + omb * trend;
                smooth = sm;
                v[k]   = sm + trend + s;
            }
        }
        #pragma unroll
        for (int q = 0; q < 8; ++q) {
            *(float4*)&tile[t * LSTRIDE + 4 * q] =
                make_float4(v[4*q+0], v[4*q+1], v[4*q+2], v[4*q+3]);
        }
        __syncthreads();

        // coalesced store: same lane mapping as the load
        #pragma unroll
        for (int j = 0; j < 8; ++j) {
            const int r = j * 32 + lrow;
            const float4 wv = *(const float4*)&tile[r * LSTRIDE + lcol];
            *(float4*)(out + (size_t)(row0 + r) * NT + c * TCOLS + lcol) = wv;
        }
        __syncthreads();  // LDS reads done before next tile overwrites
    }
}

extern "C" void kernel_launch(void* const* d_in, const int* in_sizes, int n_in,
                              void* d_out, int out_size, void* d_ws, size_t ws_size,
                              hipStream_t stream) {
    // inputs: 0=series(B*T f32), 1=series_shifts(B i32), 2=alpha, 3=beta,
    //         4=gamma(unused), 5=init_season(12 f32), 6=init_trend, 7=n_preds(unused)
    const float* series      = (const float*)d_in[0];
    const int*   shifts      = (const int*)  d_in[1];
    const float* alpha       = (const float*)d_in[2];
    const float* beta        = (const float*)d_in[3];
    const float* init_season = (const float*)d_in[5];
    const float* init_trend  = (const float*)d_in[6];
    float*       out         = (float*)d_out;

    dim3 block(BLOCK);
    dim3 grid(NB / BLOCK);
    hipLaunchKernelGGL(holtwinters_kernel, grid, block, 0, stream,
                       series, shifts, alpha, beta, init_season, init_trend, out);
}

// Round 3
// 241.369 us; speedup vs baseline: 1.3406x; 1.1010x over previous
//
#include <hip/hip_runtime.h>

#define NB 65536
#define NT 512
#define SLEN 12
#define BLOCK 256
#define ROWS 8                  // rows per block
#define CHUNKS 32               // chunks per row (one thread each)
#define CLEN 16                 // timesteps per chunk
#define CSTR 20                 // LDS floats per chunk (16 + 4 pad, keeps 16B align)
#define ROWSTR (CHUNKS * CSTR)  // 640 floats
#define YSZ (ROWS * ROWSTR)     // 5120 floats = 20 KB

// Affine-scan decomposition: x_t = A x_{t-1} + b_t with constant A.
// Each thread runs one 16-step chunk zero-init (gives res' and end-state r_c),
// per-row sequential combine over 32 chunks gives entering states S_c,
// correction out_k = res'_k + u_{k+1}.S_c with u_j = [1,1]A^j.
__global__ __launch_bounds__(BLOCK) void holtwinters_kernel(
    const float* __restrict__ series,
    const int*   __restrict__ shifts,
    const float* __restrict__ alpha_p,
    const float* __restrict__ beta_p,
    const float* __restrict__ init_season,
    const float* __restrict__ trend0_p,
    float*       __restrict__ out)
{
    __shared__ __align__(16) float  y[YSZ];          // staged inputs, later outputs
    __shared__ float2 endst[ROWS * CHUNKS];          // zero-init end states
    __shared__ float2 sarr [ROWS * CHUNKS];          // entering states S_c
    __shared__ float2 u[CLEN + 1];                   // u_j = [1,1]A^j
    __shared__ float  Mm[4];                         // A^16
    __shared__ float  ss[SLEN];

    const int t    = threadIdx.x;
    const int row0 = blockIdx.x * ROWS;

    const float alpha  = alpha_p[0];
    const float beta   = beta_p[0];
    const float oma    = 1.0f - alpha;
    const float omb    = 1.0f - beta;
    const float trend0 = trend0_p[0];

    if (t < SLEN) ss[t] = init_season[t];

    // constant tables (per-block, cheap): u_j row-vector and M = A^16.
    // Column convention: x' = A x, a00=oma a01=oma a10=-alpha*beta a11=beta*oma+omb
    if (t == 0) {
        const float a00 = oma, a01 = oma;
        const float a10 = -alpha * beta, a11 = beta * oma + omb;
        float p0 = 1.0f, p1 = 1.0f;                  // [1,1] A^0
        for (int j = 1; j <= CLEN; ++j) {
            const float q0 = p0 * a00 + p1 * a10;    // row-vec * A (column sums)
            const float q1 = p0 * a01 + p1 * a11;
            p0 = q0; p1 = q1;
            u[j] = make_float2(p0, p1);
        }
        float m00 = a00, m01 = a01, m10 = a10, m11 = a11;
        for (int sq = 0; sq < 4; ++sq) {             // A^2,A^4,A^8,A^16
            const float n00 = m00 * m00 + m01 * m10;
            const float n01 = m00 * m01 + m01 * m11;
            const float n10 = m10 * m00 + m11 * m10;
            const float n11 = m10 * m01 + m11 * m11;
            m00 = n00; m01 = n01; m10 = n10; m11 = n11;
        }
        Mm[0] = m00; Mm[1] = m01; Mm[2] = m10; Mm[3] = m11;
    }

    // P0: cooperative fully-coalesced load of 8 rows x 512 floats -> LDS
    {
        const float4* __restrict__ src = (const float4*)(series + (size_t)row0 * NT);
        #pragma unroll
        for (int i = 0; i < 4; ++i) {
            const int g   = t + i * BLOCK;   // float4 index, 0..1023
            const int r   = g >> 7;          // 128 float4 per row
            const int col = (g & 127) * 4;
            const int c   = col >> 4, k = col & 15;
            const float4 v = src[g];
            *(float4*)&y[r * ROWSTR + c * CSTR + k] = v;
        }
    }
    __syncthreads();

    // P1: per-thread zero-init chunk run (chunk 0 runs exact)
    const int r = t >> 5;        // row within block
    const int c = t & 31;        // chunk
    const int shift = shifts[row0 + r];
    int sidx = ((c * CLEN - shift) % SLEN + SLEN) % SLEN;

    float o[CLEN];
    float smooth = 0.0f, trend = 0.0f;
    {
        const float* yb = &y[r * ROWSTR + c * CSTR];
        #pragma unroll
        for (int q = 0; q < 4; ++q) {
            const float4 yv = *(const float4*)(yb + 4 * q);
            const float ya[4] = {yv.x, yv.y, yv.z, yv.w};
            #pragma unroll
            for (int kk = 0; kk < 4; ++kk) {
                const int k = 4 * q + kk;
                const float s = ss[sidx];
                sidx = (sidx + 1 == SLEN) ? 0 : sidx + 1;
                const float yy = ya[kk];
                if (c == 0 && k == 0) {
                    smooth = yy;             // t==0: res0 = y0 + init_trend
                    trend  = trend0;
                    o[0]   = smooth + trend;
                } else {
                    const float st = smooth + trend;
                    const float sm = alpha * (yy - s) + oma * st;
                    trend  = beta * (sm - smooth) + omb * trend;
                    smooth = sm;
                    o[k]   = sm + trend + s;
                }
            }
        }
    }
    endst[t] = make_float2(smooth, trend);   // endst[r*32 + c]
    __syncthreads();

    // P2: per-row sequential combine (one thread per row)
    if (c == 0) {
        const float m00 = Mm[0], m01 = Mm[1], m10 = Mm[2], m11 = Mm[3];
        float2 e0 = endst[r * CHUNKS + 0];   // chunk 0 end state is exact
        float Sx = e0.x, Sy = e0.y;
        sarr[r * CHUNKS + 1] = make_float2(Sx, Sy);
        for (int cc = 2; cc < CHUNKS; ++cc) {
            const float2 rr = endst[r * CHUNKS + cc - 1];
            const float nx = m00 * Sx + m01 * Sy + rr.x;   // S' = M S + r
            const float ny = m10 * Sx + m11 * Sy + rr.y;
            Sx = nx; Sy = ny;
            sarr[r * CHUNKS + cc] = make_float2(Sx, Sy);
        }
    }
    __syncthreads();

    // P3: correction (registers only), then stage outputs back into y region
    if (c != 0) {
        const float2 S = sarr[r * CHUNKS + c];
        #pragma unroll
        for (int k = 0; k < CLEN; ++k) {
            const float2 uk = u[k + 1];
            o[k] += uk.x * S.x + uk.y * S.y;
        }
    }
    {
        float* yb = &y[r * ROWSTR + c * CSTR];
        #pragma unroll
        for (int q = 0; q < 4; ++q)
            *(float4*)(yb + 4 * q) =
                make_float4(o[4*q], o[4*q+1], o[4*q+2], o[4*q+3]);
    }
    __syncthreads();

    // P4: cooperative fully-coalesced store LDS -> global (full 128B lines)
    {
        float4* __restrict__ dst = (float4*)(out + (size_t)row0 * NT);
        #pragma unroll
        for (int i = 0; i < 4; ++i) {
            const int g   = t + i * BLOCK;
            const int rr  = g >> 7;
            const int col = (g & 127) * 4;
            const int cc  = col >> 4, kk = col & 15;
            dst[g] = *(const float4*)&y[rr * ROWSTR + cc * CSTR + kk];
        }
    }
}

extern "C" void kernel_launch(void* const* d_in, const int* in_sizes, int n_in,
                              void* d_out, int out_size, void* d_ws, size_t ws_size,
                              hipStream_t stream) {
    // inputs: 0=series(B*T f32), 1=series_shifts(B i32), 2=alpha, 3=beta,
    //         4=gamma(unused), 5=init_season(12 f32), 6=init_trend, 7=n_preds(unused)
    const float* series      = (const float*)d_in[0];
    const int*   shifts      = (const int*)  d_in[1];
    const float* alpha       = (const float*)d_in[2];
    const float* beta        = (const float*)d_in[3];
    const float* init_season = (const float*)d_in[5];
    const float* init_trend  = (const float*)d_in[6];
    float*       out         = (float*)d_out;

    dim3 block(BLOCK);
    dim3 grid(NB / ROWS);
    hipLaunchKernelGGL(holtwinters_kernel, grid, block, 0, stream,
                       series, shifts, alpha, beta, init_season, init_trend, out);
}